// Round 7
// baseline (172.176 us; speedup 1.0000x reference)
//
#include <hip/hip_runtime.h>

#define NN 3072
#define FF 512
#define HH 8
#define DD 64
#define SLOPEV 0.2f
#define CH2 64
#define NC2 (NN/CH2)   // 48

typedef __bf16  bf16x8 __attribute__((ext_vector_type(8)));
typedef __bf16  bf16x4 __attribute__((ext_vector_type(4)));
typedef short   s16x8  __attribute__((ext_vector_type(8)));
typedef float   f32x4  __attribute__((ext_vector_type(4)));
typedef unsigned long long u64;

#define MFMA16(a,b,c) __builtin_amdgcn_mfma_f32_16x16x32_bf16((a),(b),(c),0,0,0)

__device__ __forceinline__ short f2bf(float x){ __bf16 b=(__bf16)x; return __builtin_bit_cast(short,b); }
__device__ __forceinline__ float bf2f(short s){ return (float)__builtin_bit_cast(__bf16,s); }
__device__ __forceinline__ bf16x8 ldbf8(const short* p){ return __builtin_bit_cast(bf16x8, *(const s16x8*)p); }

// global -> LDS async 16B/lane (dest = wave-uniform base + lane*16; source per-lane)
__device__ __forceinline__ void gload16(const void* g, void* l){
  __builtin_amdgcn_global_load_lds(
      (const __attribute__((address_space(1))) void*)(uintptr_t)g,
      (__attribute__((address_space(3))) void*)(uint32_t)(uintptr_t)l, 16, 0, 0);
}

// ---- K0a: split h (fp32) into bf16 hi/lo ----
__global__ __launch_bounds__(256) void k_split_h(const float* __restrict__ h,
    short* __restrict__ hhi, short* __restrict__ hlo){
  size_t base = ((size_t)blockIdx.x*256 + threadIdx.x)*8;
  float4 v0 = *(const float4*)(h+base);
  float4 v1 = *(const float4*)(h+base+4);
  float vv[8] = {v0.x,v0.y,v0.z,v0.w,v1.x,v1.y,v1.z,v1.w};
  s16x8 hi, lo;
  #pragma unroll
  for (int j=0;j<8;j++){ short s=f2bf(vv[j]); hi[j]=s; lo[j]=f2bf(vv[j]-bf2f(s)); }
  *(s16x8*)(hhi+base)=hi; *(s16x8*)(hlo+base)=lo;
}

// ---- K0b: W[h][f][d] -> WT[h][d][f] bf16 hi/lo, plus wa = W @ a (fp32) ----
__global__ __launch_bounds__(64) void k_wt(const float* __restrict__ W, const float* __restrict__ a,
    short* __restrict__ wthi, short* __restrict__ wtlo,
    float* __restrict__ wasrc, float* __restrict__ wadst){
  int h = blockIdx.y, f0 = blockIdx.x*8, d = threadIdx.x;
  float asv = a[h*2*DD + d];
  float adv = a[h*2*DD + DD + d];
  s16x8 vh, vl;
  #pragma unroll
  for (int j=0;j<8;j++){
    float v = W[((size_t)h*FF + f0 + j)*DD + d];
    short s = f2bf(v); vh[j]=s; vl[j]=f2bf(v-bf2f(s));
    float ws_ = v*asv, wd_ = v*adv;
    #pragma unroll
    for (int m=1;m<64;m<<=1){ ws_ += __shfl_xor(ws_,m,64); wd_ += __shfl_xor(wd_,m,64); }
    if (d==0){ wasrc[h*FF+f0+j]=ws_; wadst[h*FF+f0+j]=wd_; }
  }
  size_t o = ((size_t)h*DD + d)*FF + f0;
  *(s16x8*)(wthi+o)=vh; *(s16x8*)(wtlo+o)=vl;
}

// ---- K0c: bit-pack adj via ballot ----
__global__ __launch_bounds__(256) void k_pack(const int* __restrict__ adj, u64* __restrict__ padj){
  int idx = blockIdx.x*256 + threadIdx.x;
  u64 b = __ballot(adj[idx] > 0);
  if ((threadIdx.x & 63) == 0) padj[idx>>6] = b;
}

// ---- K1: src/dst for ALL heads, h read once per row ----
__global__ __launch_bounds__(256) void k_srcdst(const float* __restrict__ h,
    const float* __restrict__ wasrc, const float* __restrict__ wadst,
    float* __restrict__ src, float* __restrict__ dst){
  int n = blockIdx.x*4 + (threadIdx.x>>6);
  int lane = threadIdx.x & 63;
  const float* hp = h + (size_t)n*FF + lane*8;
  float4 x0 = *(const float4*)hp, x1 = *(const float4*)(hp+4);
  float xs[8] = {x0.x,x0.y,x0.z,x0.w,x1.x,x1.y,x1.z,x1.w};
  float ps[HH], pd[HH];
  #pragma unroll
  for (int hh=0; hh<HH; hh++){
    const float* sp = wasrc + (size_t)hh*FF + lane*8;
    const float* dp = wadst + (size_t)hh*FF + lane*8;
    float4 s0 = *(const float4*)sp, s1 = *(const float4*)(sp+4);
    float4 t0 = *(const float4*)dp, t1 = *(const float4*)(dp+4);
    ps[hh] = xs[0]*s0.x + xs[1]*s0.y + xs[2]*s0.z + xs[3]*s0.w
           + xs[4]*s1.x + xs[5]*s1.y + xs[6]*s1.z + xs[7]*s1.w;
    pd[hh] = xs[0]*t0.x + xs[1]*t0.y + xs[2]*t0.z + xs[3]*t0.w
           + xs[4]*t1.x + xs[5]*t1.y + xs[6]*t1.z + xs[7]*t1.w;
  }
  #pragma unroll
  for (int m=1;m<64;m<<=1){
    #pragma unroll
    for (int hh=0; hh<HH; hh++){ ps[hh] += __shfl_xor(ps[hh],m,64); pd[hh] += __shfl_xor(pd[hh],m,64); }
  }
  if (lane==0){
    #pragma unroll
    for (int hh=0; hh<HH; hh++){ src[hh*NN+n]=ps[hh]; dst[hh*NN+n]=pd[hh]; }
  }
}

// ---- K2: ht = h @ W[h] via split-bf16 MFMA; store htT[h][d][n] bf16 hi/lo ----
__global__ __launch_bounds__(128) void k_ht(const short* __restrict__ hhi, const short* __restrict__ hlo,
    const short* __restrict__ wthi, const short* __restrict__ wtlo,
    short* __restrict__ hthi, short* __restrict__ htlo){
  int h = blockIdx.y, n0 = blockIdx.x*32;
  int w = threadIdx.x>>6, lane = threadIdx.x&63;
  int r15 = lane&15, g = lane>>4;
  int arow = n0 + w*16 + r15;
  f32x4 acc[4] = {{0.f,0.f,0.f,0.f},{0.f,0.f,0.f,0.f},{0.f,0.f,0.f,0.f},{0.f,0.f,0.f,0.f}};
  const short* ha = hhi + (size_t)arow*FF + g*8;
  const short* la = hlo + (size_t)arow*FF + g*8;
  for (int kk=0; kk<FF; kk+=32){
    bf16x8 ahi = ldbf8(ha+kk), alo = ldbf8(la+kk);
    #pragma unroll
    for (int c=0;c<4;c++){
      size_t bo = ((size_t)h*DD + c*16 + r15)*FF + g*8 + kk;
      bf16x8 bh = ldbf8(wthi + bo), bl = ldbf8(wtlo + bo);
      acc[c] = MFMA16(ahi,bh,acc[c]);
      acc[c] = MFMA16(ahi,bl,acc[c]);
      acc[c] = MFMA16(alo,bh,acc[c]);
    }
  }
  #pragma unroll
  for (int c=0;c<4;c++){
    #pragma unroll
    for (int r=0;r<4;r++){
      float v = acc[c][r];
      short s = f2bf(v); short sl = f2bf(v - bf2f(s));
      int n = n0 + w*16 + g*4 + r;
      size_t o = ((size_t)h*DD + c*16 + r15)*NN + n;
      hthi[o]=s; htlo[o]=sl;
    }
  }
}

// ---- K3: fused masked-softmax + att write + hp; pipelined global_load_lds staging ----
// grid 768 1-D; h = bid&7 (XCD-head affinity), n0 = (bid>>3)*32. 512 thr, 40KB LDS, 4 blk/CU.
// A/B vs round 6: att/out stores are CACHED (not nontemporal).
__global__ __launch_bounds__(512, 8) void k_att(const u64* __restrict__ padj,
    const float* __restrict__ src, const float* __restrict__ dst,
    const short* __restrict__ hthi, const short* __restrict__ htlo,
    float* __restrict__ dout){
  __shared__ short hA[64][CH2], lA[64][CH2], hB[64][CH2], lB[64][CH2];  // 4 x 8KB
  __shared__ short pA[32][CH2], pB[32][CH2];                            // 2 x 4KB
  const size_t OUTOFF = (size_t)NN*HH*DD;
  int bid = blockIdx.x;
  int h = bid & 7, n0 = (bid >> 3) * 32;
  int t = threadIdx.x;
  int r = t>>4, j = t&15;
  int nrow = n0 + r;
  float srcv = src[h*NN + nrow];
  const float* dsth = dst + h*NN;
  const u64* arow = padj + (size_t)nrow*(NN/64);

  // staging map: thread t -> htT row drow = t>>3, source column-slot pre-swizzled
  int wv = t>>6, lane = t&63, r15 = lane&15, g = lane>>4;
  int cblk = wv&3, nh = wv>>2;
  int drow = t>>3;
  int sslot = (t&7) ^ (drow&7);
  const short* gh = hthi + ((size_t)(h*DD) + drow)*NN + sslot*8;
  const short* gl = htlo + ((size_t)(h*DD) + drow)*NN + sslot*8;

  // issue chunk-0 staging now; it lands during sweep A
  gload16(gh, &hA[wv*8][0]);
  gload16(gl, &lA[wv*8][0]);

  // ---- sweep A: row sums (packed adj + broadcast dst), 128-wide chunks ----
  float psum = 0.f;
  for (int c=0;c<24;c++){
    u64 w0 = arow[c*2], w1 = arow[c*2+1];
    const float* dp = dsth + c*128 + j*4;
    float4 d0 = *(const float4*)dp, d1 = *(const float4*)(dp+64);
    float dj[8] = {d0.x,d0.y,d0.z,d0.w,d1.x,d1.y,d1.z,d1.w};
    #pragma unroll
    for (int e=0;e<8;e++){
      float ev = srcv + dj[e];
      ev = fmaxf(ev, SLOPEV*ev);
      u64 bits = (e<4) ? w0 : w1;
      float p = ((bits >> (j*4 + (e&3))) & 1ull) ? __expf(ev) : 0.f;
      psum += p;
    }
  }
  #pragma unroll
  for (int m=1;m<16;m<<=1) psum += __shfl_xor(psum, m, 64);
  float inv = (psum > 0.f) ? 1.f/psum : (1.f/(float)NN);
  bool am = !(psum > 0.f);

  // ---- sweep B: pipelined. chunk c: bits/dv prefetched; ht[c] staged in LDS. ----
  f32x4 acc = {0.f,0.f,0.f,0.f};
  float* attrow = dout + OUTOFF + ((size_t)(h*NN + nrow))*NN;
  int aoff0 = (cblk*16 + r15)*(CH2*2);
  int boff0 = (nh*16 + r15)*(CH2*2);
  int csw   = (r15&7)<<4;
  int pofs  = r*(CH2*2) + ((j*8) ^ ((r&7)<<4));

  u64 bits = arow[0];
  const float* dvp = dsth + j*4;
  float4 dv = *(const float4*)dvp;

  #pragma unroll 2
  for (int c=0;c<NC2;c++){
    short (*hc)[CH2]; short (*lc)[CH2]; short (*hn)[CH2]; short (*ln)[CH2]; short (*pc)[CH2];
    if (c&1){ hc=hB; lc=lB; hn=hA; ln=lA; pc=pB; }
    else    { hc=hA; lc=lA; hn=hB; ln=lB; pc=pA; }

    // 1. issue next chunk's staging (lands across this chunk's compute + barrier)
    if (c < NC2-1){
      gload16(gh + (c+1)*CH2, &hn[wv*8][0]);
      gload16(gl + (c+1)*CH2, &ln[wv*8][0]);
    }
    // prefetch next adj/dst
    u64 bits_n = 0; float4 dv_n = {0,0,0,0};
    if (c < NC2-1){
      bits_n = arow[c+1];
      dv_n = *(const float4*)(dvp + (c+1)*CH2);
    }
    // 2. compute p (4 values), att cached store, pt LDS write
    float o[4];
    #pragma unroll
    for (int e=0;e<4;e++){
      float ev = srcv + ((const float*)&dv)[e];
      ev = fmaxf(ev, SLOPEV*ev);
      float p = ((bits >> (j*4 + e)) & 1ull) ? __expf(ev) : 0.f;
      if (am) p = 1.f;
      o[e] = p * inv;
    }
    f32x4 s0 = {o[0],o[1],o[2],o[3]};
    *(f32x4*)(attrow + c*CH2 + j*4) = s0;
    bf16x4 pb;
    #pragma unroll
    for (int e=0;e<4;e++) pb[e] = (__bf16)o[e];
    *(bf16x4*)((char*)pc + pofs) = pb;

    // 3. barrier 1: ht[c] (issued last iter) + pt[c] ready
    __syncthreads();

    // 4. MFMA on chunk c
    const char* hcB = (const char*)hc;
    const char* lcB = (const char*)lc;
    const char* pcB = (const char*)pc;
    #pragma unroll
    for (int ks=0;ks<2;ks++){
      int kb = (g*16 + ks*64) ^ csw;
      bf16x8 bf = *(const bf16x8*)(pcB + boff0 + kb);
      bf16x8 ah = *(const bf16x8*)(hcB + aoff0 + kb);
      bf16x8 al = *(const bf16x8*)(lcB + aoff0 + kb);
      acc = MFMA16(ah, bf, acc);
      acc = MFMA16(al, bf, acc);
    }
    // 5. barrier 2 (bare): protect hc from next iteration's staging overwrite
    __builtin_amdgcn_s_barrier();

    bits = bits_n; dv = dv_n;
  }

  // ---- epilogue: acc normalized already; coalesced cached out store ----
  int n = n0 + nh*16 + r15;
  size_t ob = (size_t)n*(HH*DD) + h*DD + cblk*16 + g*4;
  *(f32x4*)(dout+ob) = acc;
}

extern "C" void kernel_launch(void* const* d_in, const int* in_sizes, int n_in,
                              void* d_out, int out_size, void* d_ws, size_t ws_size,
                              hipStream_t stream) {
  const float* h   = (const float*)d_in[0];
  const int*   adj = (const int*)d_in[1];
  const float* W   = (const float*)d_in[2];
  const float* a   = (const float*)d_in[3];
  float* out = (float*)d_out;

  short* hhi  = (short*)d_ws;
  short* hlo  = hhi  + (size_t)NN*FF;
  short* wthi = hlo  + (size_t)NN*FF;
  short* wtlo = wthi + (size_t)HH*DD*FF;
  short* hthi = wtlo + (size_t)HH*DD*FF;
  short* htlo = hthi + (size_t)HH*DD*NN;
  float* wasrc= (float*)(htlo + (size_t)HH*DD*NN);
  float* wadst= wasrc + HH*FF;
  float* srcb = wadst + HH*FF;
  float* dstb = srcb + HH*NN;
  u64*   padj = (u64*)(dstb + HH*NN);

  k_split_h<<<dim3(NN*FF/(256*8)), 256, 0, stream>>>(h, hhi, hlo);
  k_wt     <<<dim3(FF/8, HH), 64, 0, stream>>>(W, a, wthi, wtlo, wasrc, wadst);
  k_pack   <<<dim3(NN*NN/256), 256, 0, stream>>>(adj, padj);
  k_srcdst <<<dim3(NN/4), 256, 0, stream>>>(h, wasrc, wadst, srcb, dstb);
  k_ht     <<<dim3(NN/32, HH), 128, 0, stream>>>(hhi, hlo, wthi, wtlo, hthi, htlo);
  k_att    <<<dim3(NN/32*HH), 512, 0, stream>>>(padj, srcb, dstb, hthi, htlo, out);
}

// Round 8
// 153.663 us; speedup vs baseline: 1.1205x; 1.1205x over previous
//
#include <hip/hip_runtime.h>

#define NN 3072
#define FF 512
#define HH 8
#define DD 64
#define SLOPEV 0.2f
#define CH2 64
#define NC2 (NN/CH2)   // 48

typedef __bf16  bf16x8 __attribute__((ext_vector_type(8)));
typedef __bf16  bf16x4 __attribute__((ext_vector_type(4)));
typedef short   s16x8  __attribute__((ext_vector_type(8)));
typedef float   f32x4  __attribute__((ext_vector_type(4)));
typedef unsigned long long u64;

#define MFMA16(a,b,c) __builtin_amdgcn_mfma_f32_16x16x32_bf16((a),(b),(c),0,0,0)

__device__ __forceinline__ short f2bf(float x){ __bf16 b=(__bf16)x; return __builtin_bit_cast(short,b); }
__device__ __forceinline__ float bf2f(short s){ return (float)__builtin_bit_cast(__bf16,s); }
__device__ __forceinline__ bf16x8 ldbf8(const short* p){ return __builtin_bit_cast(bf16x8, *(const s16x8*)p); }

// global -> LDS async 16B/lane (dest = wave-uniform base + lane*16; source per-lane)
__device__ __forceinline__ void gload16(const void* g, void* l){
  __builtin_amdgcn_global_load_lds(
      (const __attribute__((address_space(1))) void*)(uintptr_t)g,
      (__attribute__((address_space(3))) void*)(uint32_t)(uintptr_t)l, 16, 0, 0);
}

// ---- K0a: split h (fp32) into bf16 hi/lo ----
__global__ __launch_bounds__(256) void k_split_h(const float* __restrict__ h,
    short* __restrict__ hhi, short* __restrict__ hlo){
  size_t base = ((size_t)blockIdx.x*256 + threadIdx.x)*8;
  float4 v0 = *(const float4*)(h+base);
  float4 v1 = *(const float4*)(h+base+4);
  float vv[8] = {v0.x,v0.y,v0.z,v0.w,v1.x,v1.y,v1.z,v1.w};
  s16x8 hi, lo;
  #pragma unroll
  for (int j=0;j<8;j++){ short s=f2bf(vv[j]); hi[j]=s; lo[j]=f2bf(vv[j]-bf2f(s)); }
  *(s16x8*)(hhi+base)=hi; *(s16x8*)(hlo+base)=lo;
}

// ---- K0b: W[h][f][d] -> WT[h][d][f] bf16 hi/lo, plus wa = W @ a (fp32) ----
__global__ __launch_bounds__(64) void k_wt(const float* __restrict__ W, const float* __restrict__ a,
    short* __restrict__ wthi, short* __restrict__ wtlo,
    float* __restrict__ wasrc, float* __restrict__ wadst){
  int h = blockIdx.y, f0 = blockIdx.x*8, d = threadIdx.x;
  float asv = a[h*2*DD + d];
  float adv = a[h*2*DD + DD + d];
  s16x8 vh, vl;
  #pragma unroll
  for (int j=0;j<8;j++){
    float v = W[((size_t)h*FF + f0 + j)*DD + d];
    short s = f2bf(v); vh[j]=s; vl[j]=f2bf(v-bf2f(s));
    float ws_ = v*asv, wd_ = v*adv;
    #pragma unroll
    for (int m=1;m<64;m<<=1){ ws_ += __shfl_xor(ws_,m,64); wd_ += __shfl_xor(wd_,m,64); }
    if (d==0){ wasrc[h*FF+f0+j]=ws_; wadst[h*FF+f0+j]=wd_; }
  }
  size_t o = ((size_t)h*DD + d)*FF + f0;
  *(s16x8*)(wthi+o)=vh; *(s16x8*)(wtlo+o)=vl;
}

// ---- K0c: bit-pack adj via ballot ----
__global__ __launch_bounds__(256) void k_pack(const int* __restrict__ adj, u64* __restrict__ padj){
  int idx = blockIdx.x*256 + threadIdx.x;
  u64 b = __ballot(adj[idx] > 0);
  if ((threadIdx.x & 63) == 0) padj[idx>>6] = b;
}

// ---- K1: src/dst for ALL heads, h read once per row ----
__global__ __launch_bounds__(256) void k_srcdst(const float* __restrict__ h,
    const float* __restrict__ wasrc, const float* __restrict__ wadst,
    float* __restrict__ src, float* __restrict__ dst){
  int n = blockIdx.x*4 + (threadIdx.x>>6);
  int lane = threadIdx.x & 63;
  const float* hp = h + (size_t)n*FF + lane*8;
  float4 x0 = *(const float4*)hp, x1 = *(const float4*)(hp+4);
  float xs[8] = {x0.x,x0.y,x0.z,x0.w,x1.x,x1.y,x1.z,x1.w};
  float ps[HH], pd[HH];
  #pragma unroll
  for (int hh=0; hh<HH; hh++){
    const float* sp = wasrc + (size_t)hh*FF + lane*8;
    const float* dp = wadst + (size_t)hh*FF + lane*8;
    float4 s0 = *(const float4*)sp, s1 = *(const float4*)(sp+4);
    float4 t0 = *(const float4*)dp, t1 = *(const float4*)(dp+4);
    ps[hh] = xs[0]*s0.x + xs[1]*s0.y + xs[2]*s0.z + xs[3]*s0.w
           + xs[4]*s1.x + xs[5]*s1.y + xs[6]*s1.z + xs[7]*s1.w;
    pd[hh] = xs[0]*t0.x + xs[1]*t0.y + xs[2]*t0.z + xs[3]*t0.w
           + xs[4]*t1.x + xs[5]*t1.y + xs[6]*t1.z + xs[7]*t1.w;
  }
  #pragma unroll
  for (int m=1;m<64;m<<=1){
    #pragma unroll
    for (int hh=0; hh<HH; hh++){ ps[hh] += __shfl_xor(ps[hh],m,64); pd[hh] += __shfl_xor(pd[hh],m,64); }
  }
  if (lane==0){
    #pragma unroll
    for (int hh=0; hh<HH; hh++){ src[hh*NN+n]=ps[hh]; dst[hh*NN+n]=pd[hh]; }
  }
}

// ---- K2: ht = h @ W[h] via split-bf16 MFMA; store htT[h][d][n] bf16 hi/lo ----
__global__ __launch_bounds__(128) void k_ht(const short* __restrict__ hhi, const short* __restrict__ hlo,
    const short* __restrict__ wthi, const short* __restrict__ wtlo,
    short* __restrict__ hthi, short* __restrict__ htlo){
  int h = blockIdx.y, n0 = blockIdx.x*32;
  int w = threadIdx.x>>6, lane = threadIdx.x&63;
  int r15 = lane&15, g = lane>>4;
  int arow = n0 + w*16 + r15;
  f32x4 acc[4] = {{0.f,0.f,0.f,0.f},{0.f,0.f,0.f,0.f},{0.f,0.f,0.f,0.f},{0.f,0.f,0.f,0.f}};
  const short* ha = hhi + (size_t)arow*FF + g*8;
  const short* la = hlo + (size_t)arow*FF + g*8;
  for (int kk=0; kk<FF; kk+=32){
    bf16x8 ahi = ldbf8(ha+kk), alo = ldbf8(la+kk);
    #pragma unroll
    for (int c=0;c<4;c++){
      size_t bo = ((size_t)h*DD + c*16 + r15)*FF + g*8 + kk;
      bf16x8 bh = ldbf8(wthi + bo), bl = ldbf8(wtlo + bo);
      acc[c] = MFMA16(ahi,bh,acc[c]);
      acc[c] = MFMA16(ahi,bl,acc[c]);
      acc[c] = MFMA16(alo,bh,acc[c]);
    }
  }
  #pragma unroll
  for (int c=0;c<4;c++){
    #pragma unroll
    for (int r=0;r<4;r++){
      float v = acc[c][r];
      short s = f2bf(v); short sl = f2bf(v - bf2f(s));
      int n = n0 + w*16 + g*4 + r;
      size_t o = ((size_t)h*DD + c*16 + r15)*NN + n;
      hthi[o]=s; htlo[o]=sl;
    }
  }
}

// ---- K3: fused masked-softmax + att write + hp; pipelined staging, COUNTED vmcnt ----
// grid 768 1-D; h = bid&7, n0 = (bid>>3)*32. 512 thr, 40KB LDS, 4 blk/CU.
// Barrier-1 uses s_waitcnt vmcnt(5): exactly 5 vmem ops issued per iter before the
// wait (2 gload_lds + bits dwordx2 + dv dwordx4 + 1 att nt-store) -> chunk-c staging
// (issued last iter) is forced complete; current store + next-chunk loads stay in
// flight across the barrier (T4: never drain vmcnt(0) in the main loop).
__global__ __launch_bounds__(512, 8) void k_att(const u64* __restrict__ padj,
    const float* __restrict__ src, const float* __restrict__ dst,
    const short* __restrict__ hthi, const short* __restrict__ htlo,
    float* __restrict__ dout){
  __shared__ short hA[64][CH2], lA[64][CH2], hB[64][CH2], lB[64][CH2];  // 4 x 8KB
  __shared__ short pA[32][CH2], pB[32][CH2];                            // 2 x 4KB
  const size_t OUTOFF = (size_t)NN*HH*DD;
  int bid = blockIdx.x;
  int h = bid & 7, n0 = (bid >> 3) * 32;
  int t = threadIdx.x;
  int r = t>>4, j = t&15;
  int nrow = n0 + r;
  float srcv = src[h*NN + nrow];
  const float* dsth = dst + h*NN;
  const u64* arow = padj + (size_t)nrow*(NN/64);

  // staging map: thread t -> htT row drow = t>>3, source column-slot pre-swizzled
  int wv = t>>6, lane = t&63, r15 = lane&15, g = lane>>4;
  int cblk = wv&3, nh = wv>>2;
  int drow = t>>3;
  int sslot = (t&7) ^ (drow&7);
  const short* gh = hthi + ((size_t)(h*DD) + drow)*NN + sslot*8;
  const short* gl = htlo + ((size_t)(h*DD) + drow)*NN + sslot*8;

  // issue chunk-0 staging now; it lands during sweep A
  gload16(gh, &hA[wv*8][0]);
  gload16(gl, &lA[wv*8][0]);

  // ---- sweep A: row sums (packed adj + broadcast dst), 128-wide chunks ----
  float psum = 0.f;
  for (int c=0;c<24;c++){
    u64 w0 = arow[c*2], w1 = arow[c*2+1];
    const float* dp = dsth + c*128 + j*4;
    float4 d0 = *(const float4*)dp, d1 = *(const float4*)(dp+64);
    float dj[8] = {d0.x,d0.y,d0.z,d0.w,d1.x,d1.y,d1.z,d1.w};
    #pragma unroll
    for (int e=0;e<8;e++){
      float ev = srcv + dj[e];
      ev = fmaxf(ev, SLOPEV*ev);
      u64 bits = (e<4) ? w0 : w1;
      float p = ((bits >> (j*4 + (e&3))) & 1ull) ? __expf(ev) : 0.f;
      psum += p;
    }
  }
  #pragma unroll
  for (int m=1;m<16;m<<=1) psum += __shfl_xor(psum, m, 64);
  float inv = (psum > 0.f) ? 1.f/psum : (1.f/(float)NN);
  bool am = !(psum > 0.f);

  // ---- sweep B: pipelined, counted-vmcnt barriers ----
  f32x4 acc = {0.f,0.f,0.f,0.f};
  float* attrow = dout + OUTOFF + ((size_t)(h*NN + nrow))*NN;
  int aoff0 = (cblk*16 + r15)*(CH2*2);
  int boff0 = (nh*16 + r15)*(CH2*2);
  int csw   = (r15&7)<<4;
  int pofs  = r*(CH2*2) + ((j*8) ^ ((r&7)<<4));

  u64 bits = arow[0];
  const float* dvp = dsth + j*4;
  float4 dv = *(const float4*)dvp;

  #pragma unroll 2
  for (int c=0;c<NC2-1;c++){
    short (*hc)[CH2]; short (*lc)[CH2]; short (*hn)[CH2]; short (*ln)[CH2]; short (*pc)[CH2];
    if (c&1){ hc=hB; lc=lB; hn=hA; ln=lA; pc=pB; }
    else    { hc=hA; lc=lA; hn=hB; ln=lB; pc=pA; }

    // 1. issue next chunk's staging (2 vmem)
    gload16(gh + (c+1)*CH2, &hn[wv*8][0]);
    gload16(gl + (c+1)*CH2, &ln[wv*8][0]);
    // 2. prefetch next adj/dst (2 vmem)
    u64 bits_n = arow[c+1];
    float4 dv_n = *(const float4*)(dvp + (c+1)*CH2);
    // 3. compute p, att nt-store (1 vmem), pt LDS write
    float o[4];
    #pragma unroll
    for (int e=0;e<4;e++){
      float ev = srcv + ((const float*)&dv)[e];
      ev = fmaxf(ev, SLOPEV*ev);
      float p = ((bits >> (j*4 + e)) & 1ull) ? __expf(ev) : 0.f;
      if (am) p = 1.f;
      o[e] = p * inv;
    }
    f32x4 s0 = {o[0],o[1],o[2],o[3]};
    __builtin_nontemporal_store(s0, (f32x4*)(attrow + c*CH2 + j*4));
    bf16x4 pb;
    #pragma unroll
    for (int e=0;e<4;e++) pb[e] = (__bf16)o[e];
    *(bf16x4*)((char*)pc + pofs) = pb;

    // 4. barrier 1: counted wait — staging(c) done; store(c)+loads(c+1) stay in flight
    __builtin_amdgcn_sched_barrier(0);
    asm volatile("s_waitcnt vmcnt(5) lgkmcnt(0)" ::: "memory");
    __builtin_amdgcn_sched_barrier(0);
    __builtin_amdgcn_s_barrier();
    __builtin_amdgcn_sched_barrier(0);

    // 5. MFMA on chunk c
    const char* hcB = (const char*)hc;
    const char* lcB = (const char*)lc;
    const char* pcB = (const char*)pc;
    #pragma unroll
    for (int ks=0;ks<2;ks++){
      int kb = (g*16 + ks*64) ^ csw;
      bf16x8 bf = *(const bf16x8*)(pcB + boff0 + kb);
      bf16x8 ah = *(const bf16x8*)(hcB + aoff0 + kb);
      bf16x8 al = *(const bf16x8*)(lcB + aoff0 + kb);
      acc = MFMA16(ah, bf, acc);
      acc = MFMA16(al, bf, acc);
    }
    // 6. barrier 2 (bare): protect LDS from next iteration's staging overwrite
    asm volatile("" ::: "memory");
    __builtin_amdgcn_s_barrier();
    __builtin_amdgcn_sched_barrier(0);

    bits = bits_n; dv = dv_n;
  }

  // ---- peeled last chunk (no staging/prefetch issued; only 1 newer vmem = store) ----
  {
    const int c = NC2-1;
    short (*hc)[CH2] = (c&1)?hB:hA; short (*lc)[CH2] = (c&1)?lB:lA;
    short (*pc)[CH2] = (c&1)?pB:pA;
    float o[4];
    #pragma unroll
    for (int e=0;e<4;e++){
      float ev = srcv + ((const float*)&dv)[e];
      ev = fmaxf(ev, SLOPEV*ev);
      float p = ((bits >> (j*4 + e)) & 1ull) ? __expf(ev) : 0.f;
      if (am) p = 1.f;
      o[e] = p * inv;
    }
    f32x4 s0 = {o[0],o[1],o[2],o[3]};
    __builtin_nontemporal_store(s0, (f32x4*)(attrow + c*CH2 + j*4));
    bf16x4 pb;
    #pragma unroll
    for (int e=0;e<4;e++) pb[e] = (__bf16)o[e];
    *(bf16x4*)((char*)pc + pofs) = pb;

    __builtin_amdgcn_sched_barrier(0);
    asm volatile("s_waitcnt vmcnt(1) lgkmcnt(0)" ::: "memory");
    __builtin_amdgcn_sched_barrier(0);
    __builtin_amdgcn_s_barrier();
    __builtin_amdgcn_sched_barrier(0);

    const char* hcB = (const char*)hc;
    const char* lcB = (const char*)lc;
    const char* pcB = (const char*)pc;
    #pragma unroll
    for (int ks=0;ks<2;ks++){
      int kb = (g*16 + ks*64) ^ csw;
      bf16x8 bf = *(const bf16x8*)(pcB + boff0 + kb);
      bf16x8 ah = *(const bf16x8*)(hcB + aoff0 + kb);
      bf16x8 al = *(const bf16x8*)(lcB + aoff0 + kb);
      acc = MFMA16(ah, bf, acc);
      acc = MFMA16(al, bf, acc);
    }
  }

  // ---- epilogue: acc normalized already; coalesced nt out store ----
  int n = n0 + nh*16 + r15;
  size_t ob = (size_t)n*(HH*DD) + h*DD + cblk*16 + g*4;
  __builtin_nontemporal_store(acc, (f32x4*)(dout+ob));
}

extern "C" void kernel_launch(void* const* d_in, const int* in_sizes, int n_in,
                              void* d_out, int out_size, void* d_ws, size_t ws_size,
                              hipStream_t stream) {
  const float* h   = (const float*)d_in[0];
  const int*   adj = (const int*)d_in[1];
  const float* W   = (const float*)d_in[2];
  const float* a   = (const float*)d_in[3];
  float* out = (float*)d_out;

  short* hhi  = (short*)d_ws;
  short* hlo  = hhi  + (size_t)NN*FF;
  short* wthi = hlo  + (size_t)NN*FF;
  short* wtlo = wthi + (size_t)HH*DD*FF;
  short* hthi = wtlo + (size_t)HH*DD*FF;
  short* htlo = hthi + (size_t)HH*DD*NN;
  float* wasrc= (float*)(htlo + (size_t)HH*DD*NN);
  float* wadst= wasrc + HH*FF;
  float* srcb = wadst + HH*FF;
  float* dstb = srcb + HH*NN;
  u64*   padj = (u64*)(dstb + HH*NN);

  k_split_h<<<dim3(NN*FF/(256*8)), 256, 0, stream>>>(h, hhi, hlo);
  k_wt     <<<dim3(FF/8, HH), 64, 0, stream>>>(W, a, wthi, wtlo, wasrc, wadst);
  k_pack   <<<dim3(NN*NN/256), 256, 0, stream>>>(adj, padj);
  k_srcdst <<<dim3(NN/4), 256, 0, stream>>>(h, wasrc, wadst, srcb, dstb);
  k_ht     <<<dim3(NN/32, HH), 128, 0, stream>>>(hhi, hlo, wthi, wtlo, hthi, htlo);
  k_att    <<<dim3(NN/32*HH), 512, 0, stream>>>(padj, srcb, dstb, hthi, htlo, out);
}